// Round 1
// baseline (4731.065 us; speedup 1.0000x reference)
//
#include <hip/hip_runtime.h>
#include <stdint.h>

#define NHID 128

// ---------------- zero workspace region ----------------
__global__ void zero_kernel(float* __restrict__ p, size_t n4) {
    size_t i = (size_t)blockIdx.x * blockDim.x + threadIdx.x;
    size_t stride = (size_t)gridDim.x * blockDim.x;
    float4* p4 = (float4*)p;
    float4 z = make_float4(0.f, 0.f, 0.f, 0.f);
    for (size_t j = i; j < n4; j += stride) p4[j] = z;
}

// ---------------- scatter-add aggregation ----------------
// block = 256 threads: two 128-lane edge slots; 32 edges per block
__global__ __launch_bounds__(256) void scatter_kernel(
    const float* __restrict__ xin, const int* __restrict__ src,
    const int* __restrict__ dst, float* __restrict__ agg,
    float* __restrict__ cnt, int E, int do_cnt) {
    int f = threadIdx.x & 127;
    int sub = threadIdx.x >> 7;           // 0 or 1
    int base = blockIdx.x * 32;
    int lim = base + 32; if (lim > E) lim = E;
    for (int e = base + sub; e < lim; e += 2) {
        int s = src[e], d = dst[e];
        atomicAdd(&agg[(size_t)d * NHID + f], xin[(size_t)s * NHID + f]);
        if (do_cnt && f == 0) atomicAdd(&cnt[d], 1.0f);
    }
}

// ---------------- fused SAGE linear + BN + ReLU ----------------
// out[i][o] = relu(bn( (agg[i]/max(cnt,1)) @ Wl + bl + x[i] @ Wr ))
// 16 nodes per block of 128 threads; thread = output column o.
__global__ __launch_bounds__(128) void node_update_kernel(
    const float* __restrict__ agg, const float* __restrict__ cnt,
    const float* __restrict__ xin,
    const float* __restrict__ Wl, const float* __restrict__ bl,
    const float* __restrict__ Wr,
    const float* __restrict__ gam, const float* __restrict__ bet,
    const float* __restrict__ mu, const float* __restrict__ var,
    float* __restrict__ out, int N) {
    __shared__ float sA[16][132];   // 132: float4-aligned rows, conflict-light
    __shared__ float sX[16][132];
    int tid = threadIdx.x;
    int node0 = blockIdx.x * 16;
    for (int i = 0; i < 16; i++) {
        int node = node0 + i;
        float c = fmaxf(cnt[node], 1.0f);
        sA[i][tid] = agg[(size_t)node * NHID + tid] * (1.0f / c);
        sX[i][tid] = xin[(size_t)node * NHID + tid];
    }
    __syncthreads();
    int o = tid;
    float acc[16];
#pragma unroll
    for (int i = 0; i < 16; i++) acc[i] = 0.f;
    for (int k = 0; k < NHID; k += 4) {
        float wl[4], wr[4];
#pragma unroll
        for (int q = 0; q < 4; q++) {
            wl[q] = Wl[(size_t)(k + q) * NHID + o];
            wr[q] = Wr[(size_t)(k + q) * NHID + o];
        }
#pragma unroll
        for (int i = 0; i < 16; i++) {
            float4 a = *(const float4*)&sA[i][k];
            float4 xx = *(const float4*)&sX[i][k];
            acc[i] += a.x * wl[0] + a.y * wl[1] + a.z * wl[2] + a.w * wl[3]
                    + xx.x * wr[0] + xx.y * wr[1] + xx.z * wr[2] + xx.w * wr[3];
        }
    }
    float scale = gam[o] * rsqrtf(var[o] + 1e-5f);
    float bias = bet[o];
    float mean = mu[o];
    float bb = bl[o];
#pragma unroll
    for (int i = 0; i < 16; i++) {
        float h = acc[i] + bb;
        h = (h - mean) * scale + bias;
        out[(size_t)(node0 + i) * NHID + o] = fmaxf(h, 0.f);
    }
}

// ---------------- fused edge classifier MLP ----------------
// 32 edges per block of 256 threads.
// repr = [h[src](128) | h[dst](128) | attr(16) | tab(16)] = 288
// z1 = relu(repr@Wc1 + bc1) [128]; z2 = relu(z1@Wc2 + bc2) [64]; out = z2@Wc3 + bc3 [3]
__global__ __launch_bounds__(256) void classifier_kernel(
    const float* __restrict__ h, const int* __restrict__ src,
    const int* __restrict__ dst,
    const float* __restrict__ attr, const float* __restrict__ tab,
    const float* __restrict__ Wc1, const float* __restrict__ bc1,
    const float* __restrict__ Wc2, const float* __restrict__ bc2,
    const float* __restrict__ Wc3, const float* __restrict__ bc3,
    float* __restrict__ out, int E) {
    __shared__ float repr[32][292];   // 292 floats: 16B-aligned rows
    __shared__ float z1s[32][132];
    __shared__ float z2s[32][68];
    int tid = threadIdx.x;
    int e0 = blockIdx.x * 32;

    { // stage edge representations: 8 threads per edge
        int el = tid >> 3, part = tid & 7;
        int e = e0 + el;
        if (e < E) {
            int s = src[e], d = dst[e];
            const float4* hs = (const float4*)(h + (size_t)s * NHID);
            const float4* hd = (const float4*)(h + (size_t)d * NHID);
            float4* r = (float4*)(&repr[el][0]);
            for (int j = part; j < 32; j += 8) r[j] = hs[j];
            for (int j = part; j < 32; j += 8) r[32 + j] = hd[j];
            if (part < 4) r[64 + part] = ((const float4*)(attr + (size_t)e * 16))[part];
            else          r[68 + (part - 4)] = ((const float4*)(tab + (size_t)e * 16))[part - 4];
        }
    }
    __syncthreads();

    { // GEMM1: thread = (edge el, output group og of 16)
        int el = tid & 31, og = tid >> 5;
        float acc[16];
#pragma unroll
        for (int i = 0; i < 16; i++) acc[i] = bc1[og * 16 + i];
        for (int k = 0; k < 288; k += 4) {
            float4 a = *(const float4*)&repr[el][k];
            float av[4] = {a.x, a.y, a.z, a.w};
#pragma unroll
            for (int q = 0; q < 4; q++) {
                const float4* w = (const float4*)(Wc1 + (size_t)(k + q) * NHID + og * 16);
#pragma unroll
                for (int p = 0; p < 4; p++) {
                    float4 wv = w[p];
                    acc[p * 4 + 0] += av[q] * wv.x;
                    acc[p * 4 + 1] += av[q] * wv.y;
                    acc[p * 4 + 2] += av[q] * wv.z;
                    acc[p * 4 + 3] += av[q] * wv.w;
                }
            }
        }
#pragma unroll
        for (int i = 0; i < 16; i++) z1s[el][og * 16 + i] = fmaxf(acc[i], 0.f);
    }
    __syncthreads();

    { // GEMM2: thread = (edge el, output group og of 8)
        int el = tid & 31, og = tid >> 5;
        float acc[8];
#pragma unroll
        for (int i = 0; i < 8; i++) acc[i] = bc2[og * 8 + i];
        for (int k = 0; k < 128; k += 4) {
            float4 a = *(const float4*)&z1s[el][k];
            float av[4] = {a.x, a.y, a.z, a.w};
#pragma unroll
            for (int q = 0; q < 4; q++) {
                const float4* w = (const float4*)(Wc2 + (size_t)(k + q) * 64 + og * 8);
                float4 w0 = w[0], w1 = w[1];
                acc[0] += av[q] * w0.x; acc[1] += av[q] * w0.y;
                acc[2] += av[q] * w0.z; acc[3] += av[q] * w0.w;
                acc[4] += av[q] * w1.x; acc[5] += av[q] * w1.y;
                acc[6] += av[q] * w1.z; acc[7] += av[q] * w1.w;
            }
        }
#pragma unroll
        for (int i = 0; i < 8; i++) z2s[el][og * 8 + i] = fmaxf(acc[i], 0.f);
    }
    __syncthreads();

    if (tid < 96) { // GEMM3: 32 edges x 3 classes
        int el = tid / 3, c = tid % 3;
        int e = e0 + el;
        if (e < E) {
            float acc = bc3[c];
#pragma unroll 8
            for (int k = 0; k < 64; k++) acc += z2s[el][k] * Wc3[k * 3 + c];
            out[(size_t)e * 3 + c] = acc;
        }
    }
}

extern "C" void kernel_launch(void* const* d_in, const int* in_sizes, int n_in,
                              void* d_out, int out_size, void* d_ws, size_t ws_size,
                              hipStream_t stream) {
    const float* x    = (const float*)d_in[0];
    const int*   ei   = (const int*)d_in[1];
    const float* attr = (const float*)d_in[2];
    const float* tab  = (const float*)d_in[3];
    const float* W1l  = (const float*)d_in[4];
    const float* b1l  = (const float*)d_in[5];
    const float* W1r  = (const float*)d_in[6];
    const float* W2l  = (const float*)d_in[7];
    const float* b2l  = (const float*)d_in[8];
    const float* W2r  = (const float*)d_in[9];
    const float* g1   = (const float*)d_in[10];
    const float* be1  = (const float*)d_in[11];
    const float* m1   = (const float*)d_in[12];
    const float* v1   = (const float*)d_in[13];
    const float* g2   = (const float*)d_in[14];
    const float* be2  = (const float*)d_in[15];
    const float* m2   = (const float*)d_in[16];
    const float* v2   = (const float*)d_in[17];
    const float* Wc1  = (const float*)d_in[18];
    const float* bc1  = (const float*)d_in[19];
    const float* Wc2  = (const float*)d_in[20];
    const float* bc2  = (const float*)d_in[21];
    const float* Wc3  = (const float*)d_in[22];
    const float* bc3  = (const float*)d_in[23];
    float* out = (float*)d_out;

    const int N = in_sizes[0] / NHID;     // 50000
    const int E = in_sizes[1] / 2;        // 800000

    // workspace layout (bytes)
    char* ws = (char*)d_ws;
    float* cnt  = (float*)ws;                                  // N floats (+pad)
    float* aggp = (float*)(ws + 201728);                       // N*128
    float* h1   = (float*)(ws + 201728 + (size_t)N * NHID * 4);
    float* h2   = (float*)(ws + 201728 + 2 * (size_t)N * NHID * 4);

    const int src_off = 0, dst_off = E;
    const int* src = ei + src_off;
    const int* dst = ei + dst_off;

    int eblocks = (E + 31) / 32;
    int nblocks = (N + 15) / 16;

    // 1) zero cnt+agg (contiguous region)
    size_t zero1_n4 = (201728 + (size_t)N * NHID * 4) / 16;
    zero_kernel<<<1024, 256, 0, stream>>>((float*)ws, zero1_n4);
    // 2) scatter x -> agg, count
    scatter_kernel<<<eblocks, 256, 0, stream>>>(x, src, dst, aggp, cnt, E, 1);
    // 3) layer1 node update -> h1
    node_update_kernel<<<nblocks, 128, 0, stream>>>(aggp, cnt, x, W1l, b1l, W1r,
                                                    g1, be1, m1, v1, h1, N);
    // 4) re-zero agg
    size_t zero2_n4 = ((size_t)N * NHID * 4) / 16;
    zero_kernel<<<1024, 256, 0, stream>>>(aggp, zero2_n4);
    // 5) scatter h1 -> agg
    scatter_kernel<<<eblocks, 256, 0, stream>>>(h1, src, dst, aggp, cnt, E, 0);
    // 6) layer2 node update -> h2
    node_update_kernel<<<nblocks, 128, 0, stream>>>(aggp, cnt, h1, W2l, b2l, W2r,
                                                    g2, be2, m2, v2, h2, N);
    // 7) fused edge classifier
    classifier_kernel<<<eblocks, 256, 0, stream>>>(h2, src, dst, attr, tab,
                                                   Wc1, bc1, Wc2, bc2, Wc3, bc3,
                                                   out, E);
}

// Round 2
// 1321.402 us; speedup vs baseline: 3.5803x; 3.5803x over previous
//
#include <hip/hip_runtime.h>
#include <stdint.h>

#define NHID 128
#define EPB 64          // edges per classifier block
#define RP  296         // padded repr row (f16 elems): 148 dw/row = 2-way-free banking
#define Z1P 136         // padded z1 row

typedef _Float16 half8 __attribute__((ext_vector_type(8)));
typedef float f32x4 __attribute__((ext_vector_type(4)));

// ---------------- zero workspace region ----------------
__global__ void zero_kernel(float* __restrict__ p, size_t n4) {
    size_t i = (size_t)blockIdx.x * blockDim.x + threadIdx.x;
    size_t stride = (size_t)gridDim.x * blockDim.x;
    float4* p4 = (float4*)p;
    float4 z = make_float4(0.f, 0.f, 0.f, 0.f);
    for (size_t j = i; j < n4; j += stride) p4[j] = z;
}

// ---------------- weight prep: fp32 -> f16, transposed ----------------
// W1T[n][k] = Wc1[k][n]  (128 x 288); W2T[n][k] = Wc2[k][n]  (64 x 128)
__global__ void prep_weights(const float* __restrict__ Wc1, const float* __restrict__ Wc2,
                             _Float16* __restrict__ W1T, _Float16* __restrict__ W2T) {
    int tid = blockIdx.x * 256 + threadIdx.x;
    if (tid < 288 * 128) {
        int n = tid / 288, k = tid % 288;
        W1T[tid] = (_Float16)Wc1[(size_t)k * 128 + n];
    }
    if (tid < 64 * 128) {
        int n = tid / 128, k = tid % 128;
        W2T[tid] = (_Float16)Wc2[(size_t)k * 64 + n];
    }
}

// ---------------- scatter-add aggregation ----------------
__global__ __launch_bounds__(256) void scatter_kernel(
    const float* __restrict__ xin, const int* __restrict__ src,
    const int* __restrict__ dst, float* __restrict__ agg,
    float* __restrict__ cnt, int E, int do_cnt) {
    int f = threadIdx.x & 127;
    int sub = threadIdx.x >> 7;
    int base = blockIdx.x * 32;
    int lim = base + 32; if (lim > E) lim = E;
    for (int e = base + sub; e < lim; e += 2) {
        int s = src[e], d = dst[e];
        atomicAdd(&agg[(size_t)d * NHID + f], xin[(size_t)s * NHID + f]);
        if (do_cnt && f == 0) atomicAdd(&cnt[d], 1.0f);
    }
}

// ---------------- fused SAGE linear + BN + ReLU ----------------
__global__ __launch_bounds__(128) void node_update_kernel(
    const float* __restrict__ agg, const float* __restrict__ cnt,
    const float* __restrict__ xin,
    const float* __restrict__ Wl, const float* __restrict__ bl,
    const float* __restrict__ Wr,
    const float* __restrict__ gam, const float* __restrict__ bet,
    const float* __restrict__ mu, const float* __restrict__ var,
    float* __restrict__ out, int N) {
    __shared__ float sA[16][132];
    __shared__ float sX[16][132];
    int tid = threadIdx.x;
    int node0 = blockIdx.x * 16;
    for (int i = 0; i < 16; i++) {
        int node = node0 + i;
        float c = fmaxf(cnt[node], 1.0f);
        sA[i][tid] = agg[(size_t)node * NHID + tid] * (1.0f / c);
        sX[i][tid] = xin[(size_t)node * NHID + tid];
    }
    __syncthreads();
    int o = tid;
    float acc[16];
#pragma unroll
    for (int i = 0; i < 16; i++) acc[i] = 0.f;
    for (int k = 0; k < NHID; k += 4) {
        float wl[4], wr[4];
#pragma unroll
        for (int q = 0; q < 4; q++) {
            wl[q] = Wl[(size_t)(k + q) * NHID + o];
            wr[q] = Wr[(size_t)(k + q) * NHID + o];
        }
#pragma unroll
        for (int i = 0; i < 16; i++) {
            float4 a = *(const float4*)&sA[i][k];
            float4 xx = *(const float4*)&sX[i][k];
            acc[i] += a.x * wl[0] + a.y * wl[1] + a.z * wl[2] + a.w * wl[3]
                    + xx.x * wr[0] + xx.y * wr[1] + xx.z * wr[2] + xx.w * wr[3];
        }
    }
    float scale = gam[o] * rsqrtf(var[o] + 1e-5f);
    float bias = bet[o];
    float mean = mu[o];
    float bb = bl[o];
#pragma unroll
    for (int i = 0; i < 16; i++) {
        float h = acc[i] + bb;
        h = (h - mean) * scale + bias;
        out[(size_t)(node0 + i) * NHID + o] = fmaxf(h, 0.f);
    }
}

// ---------------- MFMA edge classifier ----------------
// 64 edges/block, 256 threads (4 waves). Wave w owns edges [w*16, w*16+16).
// GEMM1: [16,288]@[288,128] per wave via 9 ktiles x 8 ntiles of 16x16x32 f16 MFMA
// GEMM2: [16,128]@[128,64]  via 4x4 tiles. Layer3 fp32 scalar.
__global__ __launch_bounds__(256) void classifier_mfma(
    const float* __restrict__ h, const int* __restrict__ src,
    const int* __restrict__ dst,
    const float* __restrict__ attr, const float* __restrict__ tab,
    const _Float16* __restrict__ W1T, const float* __restrict__ bc1,
    const _Float16* __restrict__ W2T, const float* __restrict__ bc2,
    const float* __restrict__ Wc3, const float* __restrict__ bc3,
    float* __restrict__ out, int E) {
    __shared__ _Float16 repr[EPB][RP];    // 37888 B
    __shared__ _Float16 z1s[EPB][Z1P];    // 17408 B
    float* z2s = (float*)&repr[0][0];     // [EPB][68] aliases repr (17408 B)

    int tid = threadIdx.x;
    int e0 = blockIdx.x * EPB;
    int lane = tid & 63;
    int wave = tid >> 6;
    int l15 = lane & 15;
    int g = lane >> 4;

    // ---- stage repr: [hs 0:128 | hd 128:256 | attr 256:272 | tab 272:288] as f16
    {
        int el = tid >> 2;        // 0..63
        int p = tid & 3;          // quarter
        int e = e0 + el; if (e >= E) e = E - 1;
        int s = src[e], d = dst[e];
        const float4* hs = (const float4*)(h + (size_t)s * NHID + p * 32);
        const float4* hd = (const float4*)(h + (size_t)d * NHID + p * 32);
#pragma unroll
        for (int j = 0; j < 4; j++) {
            float4 a = hs[2 * j], b = hs[2 * j + 1];
            half8 v;
            v[0] = (_Float16)a.x; v[1] = (_Float16)a.y; v[2] = (_Float16)a.z; v[3] = (_Float16)a.w;
            v[4] = (_Float16)b.x; v[5] = (_Float16)b.y; v[6] = (_Float16)b.z; v[7] = (_Float16)b.w;
            *(half8*)&repr[el][p * 32 + j * 8] = v;
        }
#pragma unroll
        for (int j = 0; j < 4; j++) {
            float4 a = hd[2 * j], b = hd[2 * j + 1];
            half8 v;
            v[0] = (_Float16)a.x; v[1] = (_Float16)a.y; v[2] = (_Float16)a.z; v[3] = (_Float16)a.w;
            v[4] = (_Float16)b.x; v[5] = (_Float16)b.y; v[6] = (_Float16)b.z; v[7] = (_Float16)b.w;
            *(half8*)&repr[el][128 + p * 32 + j * 8] = v;
        }
        const float* ssrc = (p < 2) ? (attr + (size_t)e * 16 + p * 8)
                                    : (tab + (size_t)e * 16 + (p - 2) * 8);
        int doff = (p < 2) ? (256 + p * 8) : (272 + (p - 2) * 8);
        float4 a = ((const float4*)ssrc)[0], b = ((const float4*)ssrc)[1];
        half8 v;
        v[0] = (_Float16)a.x; v[1] = (_Float16)a.y; v[2] = (_Float16)a.z; v[3] = (_Float16)a.w;
        v[4] = (_Float16)b.x; v[5] = (_Float16)b.y; v[6] = (_Float16)b.z; v[7] = (_Float16)b.w;
        *(half8*)&repr[el][doff] = v;
    }
    __syncthreads();

    // ---- GEMM1 ----
    {
        f32x4 acc[8];
#pragma unroll
        for (int nt = 0; nt < 8; nt++) {
            float b = bc1[nt * 16 + l15];
            acc[nt] = (f32x4){b, b, b, b};
        }
        const _Float16* wbase = W1T + (size_t)l15 * 288 + g * 8;
        const _Float16* abase = &repr[wave * 16 + l15][g * 8];
        half8 b0[8], b1[8];
#pragma unroll
        for (int nt = 0; nt < 8; nt++) b0[nt] = *(const half8*)(wbase + nt * 16 * 288);
#pragma unroll 1
        for (int kt = 0; kt < 8; kt += 2) {
#pragma unroll
            for (int nt = 0; nt < 8; nt++)
                b1[nt] = *(const half8*)(wbase + nt * 16 * 288 + (kt + 1) * 32);
            half8 af = *(const half8*)(abase + kt * 32);
#pragma unroll
            for (int nt = 0; nt < 8; nt++)
                acc[nt] = __builtin_amdgcn_mfma_f32_16x16x32_f16(af, b0[nt], acc[nt], 0, 0, 0);
#pragma unroll
            for (int nt = 0; nt < 8; nt++)
                b0[nt] = *(const half8*)(wbase + nt * 16 * 288 + (kt + 2) * 32);
            half8 af2 = *(const half8*)(abase + (kt + 1) * 32);
#pragma unroll
            for (int nt = 0; nt < 8; nt++)
                acc[nt] = __builtin_amdgcn_mfma_f32_16x16x32_f16(af2, b1[nt], acc[nt], 0, 0, 0);
        }
        half8 af = *(const half8*)(abase + 8 * 32);
#pragma unroll
        for (int nt = 0; nt < 8; nt++)
            acc[nt] = __builtin_amdgcn_mfma_f32_16x16x32_f16(af, b0[nt], acc[nt], 0, 0, 0);
        // epilogue: relu -> f16 -> z1 LDS.  D layout: col=l15, row=g*4+r
#pragma unroll
        for (int nt = 0; nt < 8; nt++)
#pragma unroll
            for (int r = 0; r < 4; r++)
                z1s[wave * 16 + g * 4 + r][nt * 16 + l15] = (_Float16)fmaxf(acc[nt][r], 0.f);
    }
    __syncthreads();

    // ---- GEMM2 ----
    {
        f32x4 acc2[4];
#pragma unroll
        for (int nt = 0; nt < 4; nt++) {
            float b = bc2[nt * 16 + l15];
            acc2[nt] = (f32x4){b, b, b, b};
        }
        const _Float16* w2base = W2T + (size_t)l15 * 128 + g * 8;
        const _Float16* a2base = &z1s[wave * 16 + l15][g * 8];
#pragma unroll
        for (int kt = 0; kt < 4; kt++) {
            half8 af = *(const half8*)(a2base + kt * 32);
#pragma unroll
            for (int nt = 0; nt < 4; nt++) {
                half8 bf = *(const half8*)(w2base + nt * 16 * 128 + kt * 32);
                acc2[nt] = __builtin_amdgcn_mfma_f32_16x16x32_f16(af, bf, acc2[nt], 0, 0, 0);
            }
        }
#pragma unroll
        for (int nt = 0; nt < 4; nt++)
#pragma unroll
            for (int r = 0; r < 4; r++)
                z2s[(size_t)(wave * 16 + g * 4 + r) * 68 + nt * 16 + l15] = fmaxf(acc2[nt][r], 0.f);
    }
    __syncthreads();

    // ---- layer 3 (fp32) ----
    if (tid < EPB * 3) {
        int el = tid / 3, c = tid - el * 3;
        int e = e0 + el;
        if (e < E) {
            float s = bc3[c];
            const float* z = z2s + (size_t)el * 68;
#pragma unroll 16
            for (int k = 0; k < 64; k++) s += z[k] * Wc3[k * 3 + c];
            out[(size_t)e * 3 + c] = s;
        }
    }
}

extern "C" void kernel_launch(void* const* d_in, const int* in_sizes, int n_in,
                              void* d_out, int out_size, void* d_ws, size_t ws_size,
                              hipStream_t stream) {
    const float* x    = (const float*)d_in[0];
    const int*   ei   = (const int*)d_in[1];
    const float* attr = (const float*)d_in[2];
    const float* tab  = (const float*)d_in[3];
    const float* W1l  = (const float*)d_in[4];
    const float* b1l  = (const float*)d_in[5];
    const float* W1r  = (const float*)d_in[6];
    const float* W2l  = (const float*)d_in[7];
    const float* b2l  = (const float*)d_in[8];
    const float* W2r  = (const float*)d_in[9];
    const float* g1   = (const float*)d_in[10];
    const float* be1  = (const float*)d_in[11];
    const float* m1   = (const float*)d_in[12];
    const float* v1   = (const float*)d_in[13];
    const float* g2   = (const float*)d_in[14];
    const float* be2  = (const float*)d_in[15];
    const float* m2   = (const float*)d_in[16];
    const float* v2   = (const float*)d_in[17];
    const float* Wc1  = (const float*)d_in[18];
    const float* bc1  = (const float*)d_in[19];
    const float* Wc2  = (const float*)d_in[20];
    const float* bc2  = (const float*)d_in[21];
    const float* Wc3  = (const float*)d_in[22];
    const float* bc3  = (const float*)d_in[23];
    float* out = (float*)d_out;

    const int N = in_sizes[0] / NHID;     // 50000
    const int E = in_sizes[1] / 2;        // 800000

    // workspace layout (bytes)
    char* ws = (char*)d_ws;
    float* cnt  = (float*)ws;                                         // N floats (+pad)
    float* aggp = (float*)(ws + 201728);                              // N*128
    float* h1   = (float*)(ws + 201728 + (size_t)N * NHID * 4);
    float* h2   = (float*)(ws + 201728 + 2 * (size_t)N * NHID * 4);
    _Float16* W1T = (_Float16*)(ws + 201728 + 3 * (size_t)N * NHID * 4);      // 128x288
    _Float16* W2T = W1T + 288 * 128;                                          // 64x128

    const int* src = ei;
    const int* dst = ei + E;

    int eblocks32 = (E + 31) / 32;
    int eblocks64 = (E + EPB - 1) / EPB;
    int nblocks = (N + 15) / 16;

    // 0) prep classifier weights (f16, transposed)
    prep_weights<<<144, 256, 0, stream>>>(Wc1, Wc2, W1T, W2T);
    // 1) zero cnt+agg
    size_t zero1_n4 = (201728 + (size_t)N * NHID * 4) / 16;
    zero_kernel<<<1024, 256, 0, stream>>>((float*)ws, zero1_n4);
    // 2) scatter x -> agg, count
    scatter_kernel<<<eblocks32, 256, 0, stream>>>(x, src, dst, aggp, cnt, E, 1);
    // 3) layer1 node update -> h1
    node_update_kernel<<<nblocks, 128, 0, stream>>>(aggp, cnt, x, W1l, b1l, W1r,
                                                    g1, be1, m1, v1, h1, N);
    // 4) re-zero agg
    size_t zero2_n4 = ((size_t)N * NHID * 4) / 16;
    zero_kernel<<<1024, 256, 0, stream>>>(aggp, zero2_n4);
    // 5) scatter h1 -> agg
    scatter_kernel<<<eblocks32, 256, 0, stream>>>(h1, src, dst, aggp, cnt, E, 0);
    // 6) layer2 node update -> h2
    node_update_kernel<<<nblocks, 128, 0, stream>>>(aggp, cnt, h1, W2l, b2l, W2r,
                                                    g2, be2, m2, v2, h2, N);
    // 7) MFMA edge classifier
    classifier_mfma<<<eblocks64, 256, 0, stream>>>(h2, src, dst, attr, tab,
                                                   W1T, bc1, W2T, bc2, Wc3, bc3,
                                                   out, E);
}

// Round 3
// 617.414 us; speedup vs baseline: 7.6627x; 2.1402x over previous
//
#include <hip/hip_runtime.h>
#include <stdint.h>

#define NHID 128
#define EPB 64          // edges per classifier tile
#define RP  296         // padded repr row (f16 elems)
#define Z1P 136         // padded z1 row (f16 elems)

typedef _Float16 half8 __attribute__((ext_vector_type(8)));
typedef float f32x4 __attribute__((ext_vector_type(4)));

// ---------------- zero (bytes/16 granularity) ----------------
__global__ void zero_kernel(float* __restrict__ p, size_t n4) {
    size_t i = (size_t)blockIdx.x * blockDim.x + threadIdx.x;
    size_t stride = (size_t)gridDim.x * blockDim.x;
    float4* p4 = (float4*)p;
    float4 z = make_float4(0.f, 0.f, 0.f, 0.f);
    for (size_t j = i; j < n4; j += stride) p4[j] = z;
}

// ---------------- weight prep: fp32 -> f16, transposed ----------------
__global__ void prep_weights(const float* __restrict__ Wc1, const float* __restrict__ Wc2,
                             _Float16* __restrict__ W1T, _Float16* __restrict__ W2T) {
    int tid = blockIdx.x * 256 + threadIdx.x;
    if (tid < 288 * 128) {
        int n = tid / 288, k = tid % 288;
        W1T[tid] = (_Float16)Wc1[(size_t)k * 128 + n];
    }
    if (tid < 64 * 128) {
        int n = tid / 128, k = tid % 128;
        W2T[tid] = (_Float16)Wc2[(size_t)k * 64 + n];
    }
}

// ---------------- CSR build ----------------
__global__ void count_kernel(const int* __restrict__ dst, int* __restrict__ deg, int E) {
    int e = blockIdx.x * 256 + threadIdx.x;
    if (e < E) atomicAdd(&deg[dst[e]], 1);
}

__global__ __launch_bounds__(1024) void scan_kernel(const int* __restrict__ deg,
                                                    int* __restrict__ rowptr,
                                                    int* __restrict__ cursor, int N) {
    __shared__ int buf[1024];
    __shared__ int carry_s;
    int tid = threadIdx.x;
    if (tid == 0) carry_s = 0;
    __syncthreads();
    for (int base = 0; base < N; base += 1024) {
        int i = base + tid;
        int v = (i < N) ? deg[i] : 0;
        buf[tid] = v;
        __syncthreads();
        int x = v;
#pragma unroll
        for (int off = 1; off < 1024; off <<= 1) {
            int y = (tid >= off) ? buf[tid - off] : 0;
            __syncthreads();
            x += y;
            buf[tid] = x;
            __syncthreads();
        }
        int carry = carry_s;
        if (i < N) {
            int excl = carry + x - v;
            rowptr[i] = excl;
            cursor[i] = excl;
        }
        __syncthreads();
        if (tid == 1023) carry_s = carry + x;
        __syncthreads();
    }
    if (tid == 0) rowptr[N] = carry_s;
}

__global__ void fill_kernel(const int* __restrict__ src, const int* __restrict__ dst,
                            int* __restrict__ cursor, int* __restrict__ ssrc, int E) {
    int e = blockIdx.x * 256 + threadIdx.x;
    if (e < E) {
        int p = atomicAdd(&cursor[dst[e]], 1);
        ssrc[p] = src[e];
    }
}

// ---------------- fused pull-aggregate + SAGE linear + BN + ReLU ----------------
// 128 threads, 16 nodes/block. Pull: agg[i][f] = sum_{e in CSR[i]} xin[ssrc[e]][f] / deg.
__global__ __launch_bounds__(128) void sage_layer(
    const float* __restrict__ xin, const int* __restrict__ rowptr,
    const int* __restrict__ ssrc,
    const float* __restrict__ Wl, const float* __restrict__ bl,
    const float* __restrict__ Wr,
    const float* __restrict__ gam, const float* __restrict__ bet,
    const float* __restrict__ mu, const float* __restrict__ var,
    float* __restrict__ out32, _Float16* __restrict__ out16, int N) {
    __shared__ float sA[16][132];
    __shared__ float sX[16][132];
    int tid = threadIdx.x;
    int node0 = blockIdx.x * 16;

    for (int i = 0; i < 16; i++) {
        int node = node0 + i;
        int rs = rowptr[node], re = rowptr[node + 1];
        float acc = 0.f;
        int e = rs;
        for (; e + 4 <= re; e += 4) {
            int s0 = ssrc[e], s1 = ssrc[e + 1], s2 = ssrc[e + 2], s3 = ssrc[e + 3];
            float v0 = xin[(size_t)s0 * NHID + tid];
            float v1 = xin[(size_t)s1 * NHID + tid];
            float v2 = xin[(size_t)s2 * NHID + tid];
            float v3 = xin[(size_t)s3 * NHID + tid];
            acc += v0 + v1 + v2 + v3;
        }
        for (; e < re; e++) acc += xin[(size_t)ssrc[e] * NHID + tid];
        int deg = re - rs;
        float inv = (deg > 0) ? (1.0f / (float)deg) : 0.f;
        sA[i][tid] = acc * inv;
        sX[i][tid] = xin[(size_t)node * NHID + tid];
    }
    __syncthreads();

    int o = tid;
    float acc[16];
#pragma unroll
    for (int i = 0; i < 16; i++) acc[i] = 0.f;
    for (int k = 0; k < NHID; k += 4) {
        float wl[4], wr[4];
#pragma unroll
        for (int q = 0; q < 4; q++) {
            wl[q] = Wl[(size_t)(k + q) * NHID + o];
            wr[q] = Wr[(size_t)(k + q) * NHID + o];
        }
#pragma unroll
        for (int i = 0; i < 16; i++) {
            float4 a = *(const float4*)&sA[i][k];
            float4 xx = *(const float4*)&sX[i][k];
            acc[i] += a.x * wl[0] + a.y * wl[1] + a.z * wl[2] + a.w * wl[3]
                    + xx.x * wr[0] + xx.y * wr[1] + xx.z * wr[2] + xx.w * wr[3];
        }
    }
    float scale = gam[o] * rsqrtf(var[o] + 1e-5f);
    float bias = bet[o];
    float mean = mu[o];
    float bb = bl[o];
#pragma unroll
    for (int i = 0; i < 16; i++) {
        float hv = acc[i] + bb;
        hv = (hv - mean) * scale + bias;
        hv = fmaxf(hv, 0.f);
        if (out32) out32[(size_t)(node0 + i) * NHID + o] = hv;
        else       out16[(size_t)(node0 + i) * NHID + o] = (_Float16)hv;
    }
}

// ---------------- MFMA edge classifier, persistent-B grid-stride ----------------
// 256 threads (4 waves), 64 edges/tile, grid-stride over tiles.
// Wave w: GEMM1 ntiles [(w&1)*4, +4), atiles [(w>>1)*2, +2); GEMM2 ntile w, all 4 atiles.
__global__ __launch_bounds__(256, 2) void classifier_mfma(
    const _Float16* __restrict__ h2f, const int* __restrict__ src,
    const int* __restrict__ dst,
    const float* __restrict__ attr, const float* __restrict__ tab,
    const _Float16* __restrict__ W1T, const float* __restrict__ bc1,
    const _Float16* __restrict__ W2T, const float* __restrict__ bc2,
    const float* __restrict__ Wc3, const float* __restrict__ bc3,
    float* __restrict__ out, int E, int ntiles) {
    __shared__ _Float16 repr[EPB][RP];    // 37888 B
    __shared__ _Float16 z1s[EPB][Z1P];    // 17408 B
    float* z2s = (float*)&repr[0][0];     // [EPB][68] aliases repr

    int tid = threadIdx.x;
    int lane = tid & 63;
    int wave = tid >> 6;
    int l15 = lane & 15;
    int g = lane >> 4;
    int ntb = (wave & 1) * 4;
    int atb = (wave >> 1) * 2;

    // persistent B fragments (VGPR-resident across the tile loop)
    half8 B1[4][9];
    const _Float16* w1base = W1T + (size_t)(ntb * 16 + l15) * 288 + g * 8;
#pragma unroll
    for (int nt = 0; nt < 4; nt++)
#pragma unroll
        for (int kt = 0; kt < 9; kt++)
            B1[nt][kt] = *(const half8*)(w1base + nt * 16 * 288 + kt * 32);
    float bias1[4];
#pragma unroll
    for (int nt = 0; nt < 4; nt++) bias1[nt] = bc1[(ntb + nt) * 16 + l15];
    half8 B2[4];
    const _Float16* w2base = W2T + (size_t)(wave * 16 + l15) * 128 + g * 8;
#pragma unroll
    for (int kt = 0; kt < 4; kt++) B2[kt] = *(const half8*)(w2base + kt * 32);
    float bias2 = bc2[wave * 16 + l15];

    for (int t = blockIdx.x; t < ntiles; t += gridDim.x) {
        int e0 = t * EPB;
        { // ---- stage repr: 4 threads/edge, f16 copies + attr/tab cvt
            int el = tid >> 2, p = tid & 3;
            int e = e0 + el; if (e >= E) e = E - 1;
            int s = src[e], d = dst[e];
            const half8* hs = (const half8*)(h2f + (size_t)s * NHID + p * 32);
            const half8* hd = (const half8*)(h2f + (size_t)d * NHID + p * 32);
            half8* r = (half8*)&repr[el][0];
#pragma unroll
            for (int j = 0; j < 4; j++) r[p * 4 + j] = hs[j];
#pragma unroll
            for (int j = 0; j < 4; j++) r[16 + p * 4 + j] = hd[j];
            const float* ssrcp = (p < 2) ? (attr + (size_t)e * 16 + p * 8)
                                         : (tab + (size_t)e * 16 + (p - 2) * 8);
            int doff = (p < 2) ? (32 + p) : (34 + (p - 2));
            float4 a = ((const float4*)ssrcp)[0], b = ((const float4*)ssrcp)[1];
            half8 v;
            v[0] = (_Float16)a.x; v[1] = (_Float16)a.y; v[2] = (_Float16)a.z; v[3] = (_Float16)a.w;
            v[4] = (_Float16)b.x; v[5] = (_Float16)b.y; v[6] = (_Float16)b.z; v[7] = (_Float16)b.w;
            r[doff] = v;
        }
        __syncthreads();

        // ---- GEMM1: 2 atiles x 4 ntiles
#pragma unroll
        for (int a2 = 0; a2 < 2; a2++) {
            const _Float16* ab = &repr[(atb + a2) * 16 + l15][g * 8];
            f32x4 acc[4];
#pragma unroll
            for (int nt = 0; nt < 4; nt++)
                acc[nt] = (f32x4){bias1[nt], bias1[nt], bias1[nt], bias1[nt]};
#pragma unroll
            for (int kt = 0; kt < 9; kt++) {
                half8 af = *(const half8*)(ab + kt * 32);
#pragma unroll
                for (int nt = 0; nt < 4; nt++)
                    acc[nt] = __builtin_amdgcn_mfma_f32_16x16x32_f16(af, B1[nt][kt], acc[nt], 0, 0, 0);
            }
#pragma unroll
            for (int nt = 0; nt < 4; nt++)
#pragma unroll
                for (int r = 0; r < 4; r++)
                    z1s[(atb + a2) * 16 + g * 4 + r][(ntb + nt) * 16 + l15] =
                        (_Float16)fmaxf(acc[nt][r], 0.f);
        }
        __syncthreads();

        // ---- GEMM2: 4 atiles x 1 ntile (wave)
#pragma unroll
        for (int a = 0; a < 4; a++) {
            const _Float16* ab = &z1s[a * 16 + l15][g * 8];
            f32x4 acc2 = (f32x4){bias2, bias2, bias2, bias2};
#pragma unroll
            for (int kt = 0; kt < 4; kt++)
                acc2 = __builtin_amdgcn_mfma_f32_16x16x32_f16(*(const half8*)(ab + kt * 32),
                                                              B2[kt], acc2, 0, 0, 0);
#pragma unroll
            for (int r = 0; r < 4; r++)
                z2s[(size_t)(a * 16 + g * 4 + r) * 68 + wave * 16 + l15] = fmaxf(acc2[r], 0.f);
        }
        __syncthreads();

        // ---- layer 3 (fp32)
        if (tid < EPB * 3) {
            int el = tid / 3, c = tid - el * 3;
            int e = e0 + el;
            if (e < E) {
                float s = bc3[c];
                const float* z = z2s + (size_t)el * 68;
#pragma unroll 16
                for (int k = 0; k < 64; k++) s += z[k] * Wc3[k * 3 + c];
                out[(size_t)e * 3 + c] = s;
            }
        }
        __syncthreads();   // protect repr/z2s before next tile's staging
    }
}

extern "C" void kernel_launch(void* const* d_in, const int* in_sizes, int n_in,
                              void* d_out, int out_size, void* d_ws, size_t ws_size,
                              hipStream_t stream) {
    const float* x    = (const float*)d_in[0];
    const int*   ei   = (const int*)d_in[1];
    const float* attr = (const float*)d_in[2];
    const float* tab  = (const float*)d_in[3];
    const float* W1l  = (const float*)d_in[4];
    const float* b1l  = (const float*)d_in[5];
    const float* W1r  = (const float*)d_in[6];
    const float* W2l  = (const float*)d_in[7];
    const float* b2l  = (const float*)d_in[8];
    const float* W2r  = (const float*)d_in[9];
    const float* g1   = (const float*)d_in[10];
    const float* be1  = (const float*)d_in[11];
    const float* m1   = (const float*)d_in[12];
    const float* v1   = (const float*)d_in[13];
    const float* g2   = (const float*)d_in[14];
    const float* be2  = (const float*)d_in[15];
    const float* m2   = (const float*)d_in[16];
    const float* v2   = (const float*)d_in[17];
    const float* Wc1  = (const float*)d_in[18];
    const float* bc1  = (const float*)d_in[19];
    const float* Wc2  = (const float*)d_in[20];
    const float* bc2  = (const float*)d_in[21];
    const float* Wc3  = (const float*)d_in[22];
    const float* bc3  = (const float*)d_in[23];
    float* out = (float*)d_out;

    const int N = in_sizes[0] / NHID;     // 50000
    const int E = in_sizes[1] / 2;        // 800000

    // workspace layout (bytes)
    char* ws = (char*)d_ws;
    int*       rowptr = (int*)(ws + 0);                 // N+1 ints
    int*       cursor = (int*)(ws + 204800);            // N ints
    int*       deg    = (int*)(ws + 409600);            // N ints
    int*       ssrc   = (int*)(ws + 614400);            // E ints
    _Float16*  W1T    = (_Float16*)(ws + 3814400);      // 128x288
    _Float16*  W2T    = (_Float16*)(ws + 3888128);      // 64x128
    float*     h1     = (float*)(ws + 3904512);         // N*128 f32
    _Float16*  h2f    = (_Float16*)(ws + 3904512 + (size_t)N * NHID * 4);  // N*128 f16

    const int* src = ei;
    const int* dst = ei + E;

    int eblocks = (E + 255) / 256;
    int nblocks = (N + 15) / 16;
    int ntiles  = (E + EPB - 1) / EPB;
    int cgrid   = ntiles < 2048 ? ntiles : 2048;

    // 0) prep classifier weights (f16, transposed)
    prep_weights<<<144, 256, 0, stream>>>(Wc1, Wc2, W1T, W2T);
    // 1) CSR build: zero deg -> count -> scan -> fill
    zero_kernel<<<64, 256, 0, stream>>>((float*)deg, 204800 / 16);
    count_kernel<<<eblocks, 256, 0, stream>>>(dst, deg, E);
    scan_kernel<<<1, 1024, 0, stream>>>(deg, rowptr, cursor, N);
    fill_kernel<<<eblocks, 256, 0, stream>>>(src, dst, cursor, ssrc, E);
    // 2) layer 1: pull + linear + BN + ReLU -> h1 (fp32)
    sage_layer<<<nblocks, 128, 0, stream>>>(x, rowptr, ssrc, W1l, b1l, W1r,
                                            g1, be1, m1, v1, h1, (_Float16*)nullptr, N);
    // 3) layer 2: pull + linear + BN + ReLU -> h2 (f16)
    sage_layer<<<nblocks, 128, 0, stream>>>(h1, rowptr, ssrc, W2l, b2l, W2r,
                                            g2, be2, m2, v2, (float*)nullptr, h2f, N);
    // 4) MFMA edge classifier
    classifier_mfma<<<cgrid, 256, 0, stream>>>(h2f, src, dst, attr, tab,
                                               W1T, bc1, W2T, bc2, Wc3, bc3,
                                               out, E, ntiles);
}

// Round 4
// 585.658 us; speedup vs baseline: 8.0782x; 1.0542x over previous
//
#include <hip/hip_runtime.h>
#include <stdint.h>

#define NHID 128
#define EPB 64          // edges per classifier tile
#define RP  296         // padded repr row (f16 elems)
#define Z1P 136         // padded z1 row (f16 elems)
#define Z2P 72          // padded z2 row (f16 elems)

typedef _Float16 half8 __attribute__((ext_vector_type(8)));
typedef float f32x4 __attribute__((ext_vector_type(4)));

// ---------------- zero (16B granularity) ----------------
__global__ void zero_kernel(float* __restrict__ p, size_t n4) {
    size_t i = (size_t)blockIdx.x * blockDim.x + threadIdx.x;
    size_t stride = (size_t)gridDim.x * blockDim.x;
    float4* p4 = (float4*)p;
    float4 z = make_float4(0.f, 0.f, 0.f, 0.f);
    for (size_t j = i; j < n4; j += stride) p4[j] = z;
}

// ---------------- weight prep: fp32 -> f16, transposed ----------------
__global__ void prep_weights(const float* __restrict__ Wc1, const float* __restrict__ Wc2,
                             const float* __restrict__ Wc3,
                             _Float16* __restrict__ W1T, _Float16* __restrict__ W2T,
                             _Float16* __restrict__ W3T) {
    int tid = blockIdx.x * 256 + threadIdx.x;
    if (tid < 288 * 128) {
        int n = tid / 288, k = tid % 288;
        W1T[tid] = (_Float16)Wc1[(size_t)k * 128 + n];
    }
    if (tid < 64 * 128) {
        int n = tid / 128, k = tid % 128;
        W2T[tid] = (_Float16)Wc2[(size_t)k * 64 + n];
    }
    if (tid < 16 * 64) {
        int n = tid / 64, k = tid % 64;
        W3T[tid] = (n < 3) ? (_Float16)Wc3[(size_t)k * 3 + n] : (_Float16)0.f;
    }
}

// ---------------- CSR build ----------------
__global__ void count_kernel(const int* __restrict__ dst, int* __restrict__ deg, int E) {
    int e = blockIdx.x * 256 + threadIdx.x;
    if (e < E) atomicAdd(&deg[dst[e]], 1);
}

// phase 1: per-block (256 elems) sum
__global__ __launch_bounds__(256) void csr_reduce(const int* __restrict__ deg,
                                                  int* __restrict__ bsum, int N) {
    __shared__ int b[256];
    int t = threadIdx.x;
    int i = blockIdx.x * 256 + t;
    int v = (i < N) ? deg[i] : 0;
    b[t] = v;
    __syncthreads();
#pragma unroll
    for (int off = 128; off > 0; off >>= 1) {
        if (t < off) b[t] += b[t + off];
        __syncthreads();
    }
    if (t == 0) bsum[blockIdx.x] = b[0];
}

// phase 2: scan block partials (nb <= 256), single block
__global__ __launch_bounds__(256) void csr_scan_partials(const int* __restrict__ bsum,
                                                         int* __restrict__ bpre,
                                                         int* __restrict__ rowptr,
                                                         int nb, int N) {
    __shared__ int b[256];
    int t = threadIdx.x;
    int v = (t < nb) ? bsum[t] : 0;
    b[t] = v;
    __syncthreads();
    int x = v;
#pragma unroll
    for (int off = 1; off < 256; off <<= 1) {
        int y = (t >= off) ? b[t - off] : 0;
        __syncthreads();
        x += y;
        b[t] = x;
        __syncthreads();
    }
    if (t < nb) bpre[t] = x - v;           // exclusive
    if (t == nb - 1) rowptr[N] = x;        // total
}

// phase 3: local scan + offset, emit rowptr & cursor
__global__ __launch_bounds__(256) void csr_emit(const int* __restrict__ deg,
                                                const int* __restrict__ bpre,
                                                int* __restrict__ rowptr,
                                                int* __restrict__ cursor, int N) {
    __shared__ int b[256];
    int t = threadIdx.x;
    int i = blockIdx.x * 256 + t;
    int v = (i < N) ? deg[i] : 0;
    b[t] = v;
    __syncthreads();
    int x = v;
#pragma unroll
    for (int off = 1; off < 256; off <<= 1) {
        int y = (t >= off) ? b[t - off] : 0;
        __syncthreads();
        x += y;
        b[t] = x;
        __syncthreads();
    }
    if (i < N) {
        int excl = bpre[blockIdx.x] + x - v;
        rowptr[i] = excl;
        cursor[i] = excl;
    }
}

__global__ void fill_kernel(const int* __restrict__ src, const int* __restrict__ dst,
                            int* __restrict__ cursor, int* __restrict__ ssrc, int E) {
    int e = blockIdx.x * 256 + threadIdx.x;
    if (e < E) {
        int p = atomicAdd(&cursor[dst[e]], 1);
        ssrc[p] = src[e];
    }
}

// ---------------- fused pull-aggregate + SAGE linear + BN + ReLU ----------------
// 256 threads, 16 nodes/block; half hh pulls nodes hh*8..hh*8+8.
__global__ __launch_bounds__(256) void sage_layer(
    const float* __restrict__ xin, const int* __restrict__ rowptr,
    const int* __restrict__ ssrc,
    const float* __restrict__ Wl, const float* __restrict__ bl,
    const float* __restrict__ Wr,
    const float* __restrict__ gam, const float* __restrict__ bet,
    const float* __restrict__ mu, const float* __restrict__ var,
    float* __restrict__ out32, _Float16* __restrict__ out16, int N) {
    __shared__ float sA[16][132];
    __shared__ float sX[16][132];
    int tid = threadIdx.x;
    int f = tid & 127;
    int hh = tid >> 7;
    int node0 = blockIdx.x * 16;

    for (int ii = 0; ii < 8; ii++) {
        int i = hh * 8 + ii;
        int node = node0 + i;
        int rs = rowptr[node], re = rowptr[node + 1];
        float acc = 0.f;
        int e = rs;
        for (; e + 8 <= re; e += 8) {
            int s0 = ssrc[e],     s1 = ssrc[e + 1], s2 = ssrc[e + 2], s3 = ssrc[e + 3];
            int s4 = ssrc[e + 4], s5 = ssrc[e + 5], s6 = ssrc[e + 6], s7 = ssrc[e + 7];
            float v0 = xin[(size_t)s0 * NHID + f];
            float v1 = xin[(size_t)s1 * NHID + f];
            float v2 = xin[(size_t)s2 * NHID + f];
            float v3 = xin[(size_t)s3 * NHID + f];
            float v4 = xin[(size_t)s4 * NHID + f];
            float v5 = xin[(size_t)s5 * NHID + f];
            float v6 = xin[(size_t)s6 * NHID + f];
            float v7 = xin[(size_t)s7 * NHID + f];
            acc += ((v0 + v1) + (v2 + v3)) + ((v4 + v5) + (v6 + v7));
        }
        for (; e < re; e++) acc += xin[(size_t)ssrc[e] * NHID + f];
        int deg = re - rs;
        float inv = (deg > 0) ? (1.0f / (float)deg) : 0.f;
        sA[i][f] = acc * inv;
        sX[i][f] = xin[(size_t)node * NHID + f];
    }
    __syncthreads();

    int o = f;
    int i0 = hh * 8;
    float acc[8];
#pragma unroll
    for (int i = 0; i < 8; i++) acc[i] = 0.f;
    for (int k = 0; k < NHID; k += 4) {
        float wl[4], wr[4];
#pragma unroll
        for (int q = 0; q < 4; q++) {
            wl[q] = Wl[(size_t)(k + q) * NHID + o];
            wr[q] = Wr[(size_t)(k + q) * NHID + o];
        }
#pragma unroll
        for (int i = 0; i < 8; i++) {
            float4 a = *(const float4*)&sA[i0 + i][k];
            float4 xx = *(const float4*)&sX[i0 + i][k];
            acc[i] += a.x * wl[0] + a.y * wl[1] + a.z * wl[2] + a.w * wl[3]
                    + xx.x * wr[0] + xx.y * wr[1] + xx.z * wr[2] + xx.w * wr[3];
        }
    }
    float scale = gam[o] * rsqrtf(var[o] + 1e-5f);
    float bias = bet[o];
    float mean = mu[o];
    float bb = bl[o];
#pragma unroll
    for (int i = 0; i < 8; i++) {
        float hv = acc[i] + bb;
        hv = (hv - mean) * scale + bias;
        hv = fmaxf(hv, 0.f);
        if (out32) out32[(size_t)(node0 + i0 + i) * NHID + o] = hv;
        else       out16[(size_t)(node0 + i0 + i) * NHID + o] = (_Float16)hv;
    }
}

// ---------------- MFMA edge classifier, persistent-B grid-stride ----------------
// 256 threads (4 waves), 64 edges/tile. launch_bounds(256,1): allow ~230 VGPR so
// B1[4][9] (144 VGPR) stays register-resident across the tile loop.
__global__ __launch_bounds__(256, 1) void classifier_mfma(
    const _Float16* __restrict__ h2f, const int* __restrict__ src,
    const int* __restrict__ dst,
    const float* __restrict__ attr, const float* __restrict__ tab,
    const _Float16* __restrict__ W1T, const float* __restrict__ bc1,
    const _Float16* __restrict__ W2T, const float* __restrict__ bc2,
    const _Float16* __restrict__ W3T, const float* __restrict__ bc3,
    float* __restrict__ out, int E, int ntiles) {
    __shared__ _Float16 repr[EPB][RP];    // 37888 B
    __shared__ _Float16 z1s[EPB][Z1P];    // 17408 B
    _Float16* z2f = &repr[0][0];          // [EPB][Z2P] aliases repr (9216 B)

    int tid = threadIdx.x;
    int lane = tid & 63;
    int wave = tid >> 6;
    int l15 = lane & 15;
    int g = lane >> 4;
    int ntb = (wave & 1) * 4;
    int atb = (wave >> 1) * 2;

    // persistent B fragments
    half8 B1[4][9];
    const _Float16* w1base = W1T + (size_t)(ntb * 16 + l15) * 288 + g * 8;
#pragma unroll
    for (int nt = 0; nt < 4; nt++)
#pragma unroll
        for (int kt = 0; kt < 9; kt++)
            B1[nt][kt] = *(const half8*)(w1base + nt * 16 * 288 + kt * 32);
    float bias1[4];
#pragma unroll
    for (int nt = 0; nt < 4; nt++) bias1[nt] = bc1[(ntb + nt) * 16 + l15];
    half8 B2[4];
    const _Float16* w2base = W2T + (size_t)(wave * 16 + l15) * 128 + g * 8;
#pragma unroll
    for (int kt = 0; kt < 4; kt++) B2[kt] = *(const half8*)(w2base + kt * 32);
    float bias2 = bc2[wave * 16 + l15];
    half8 B3[2];
#pragma unroll
    for (int kt = 0; kt < 2; kt++)
        B3[kt] = *(const half8*)(W3T + (size_t)l15 * 64 + kt * 32 + g * 8);
    float bias3 = bc3[l15 < 3 ? l15 : 2];

    for (int t = blockIdx.x; t < ntiles; t += gridDim.x) {
        int e0 = t * EPB;
        { // ---- stage repr
            int el = tid >> 2, p = tid & 3;
            int e = e0 + el; if (e >= E) e = E - 1;
            int s = src[e], d = dst[e];
            const half8* hs = (const half8*)(h2f + (size_t)s * NHID + p * 32);
            const half8* hd = (const half8*)(h2f + (size_t)d * NHID + p * 32);
            half8* r = (half8*)&repr[el][0];
#pragma unroll
            for (int j = 0; j < 4; j++) r[p * 4 + j] = hs[j];
#pragma unroll
            for (int j = 0; j < 4; j++) r[16 + p * 4 + j] = hd[j];
            const float* ssrcp = (p < 2) ? (attr + (size_t)e * 16 + p * 8)
                                         : (tab + (size_t)e * 16 + (p - 2) * 8);
            int doff = (p < 2) ? (32 + p) : (34 + (p - 2));
            float4 a = ((const float4*)ssrcp)[0], b = ((const float4*)ssrcp)[1];
            half8 v;
            v[0] = (_Float16)a.x; v[1] = (_Float16)a.y; v[2] = (_Float16)a.z; v[3] = (_Float16)a.w;
            v[4] = (_Float16)b.x; v[5] = (_Float16)b.y; v[6] = (_Float16)b.z; v[7] = (_Float16)b.w;
            r[doff] = v;
        }
        __syncthreads();

        // ---- GEMM1: 2 atiles x 4 ntiles, B resident
#pragma unroll
        for (int a2 = 0; a2 < 2; a2++) {
            const _Float16* ab = &repr[(atb + a2) * 16 + l15][g * 8];
            f32x4 acc[4];
#pragma unroll
            for (int nt = 0; nt < 4; nt++)
                acc[nt] = (f32x4){bias1[nt], bias1[nt], bias1[nt], bias1[nt]};
#pragma unroll
            for (int kt = 0; kt < 9; kt++) {
                half8 af = *(const half8*)(ab + kt * 32);
#pragma unroll
                for (int nt = 0; nt < 4; nt++)
                    acc[nt] = __builtin_amdgcn_mfma_f32_16x16x32_f16(af, B1[nt][kt], acc[nt], 0, 0, 0);
            }
#pragma unroll
            for (int nt = 0; nt < 4; nt++)
#pragma unroll
                for (int r = 0; r < 4; r++)
                    z1s[(atb + a2) * 16 + g * 4 + r][(ntb + nt) * 16 + l15] =
                        (_Float16)fmaxf(acc[nt][r], 0.f);
        }
        __syncthreads();

        // ---- GEMM2: 4 atiles x 1 ntile (wave) -> z2f (f16, aliases repr)
#pragma unroll
        for (int a = 0; a < 4; a++) {
            const _Float16* ab = &z1s[a * 16 + l15][g * 8];
            f32x4 acc2 = (f32x4){bias2, bias2, bias2, bias2};
#pragma unroll
            for (int kt = 0; kt < 4; kt++)
                acc2 = __builtin_amdgcn_mfma_f32_16x16x32_f16(*(const half8*)(ab + kt * 32),
                                                              B2[kt], acc2, 0, 0, 0);
#pragma unroll
            for (int r = 0; r < 4; r++)
                z2f[(size_t)(a * 16 + g * 4 + r) * Z2P + wave * 16 + l15] =
                    (_Float16)fmaxf(acc2[r], 0.f);
        }
        __syncthreads();

        // ---- layer 3 via MFMA: wave handles atile=wave (16 edges)
        {
            const _Float16* ab = z2f + (size_t)(wave * 16 + l15) * Z2P + g * 8;
            f32x4 acc3 = (f32x4){0.f, 0.f, 0.f, 0.f};
#pragma unroll
            for (int kt = 0; kt < 2; kt++)
                acc3 = __builtin_amdgcn_mfma_f32_16x16x32_f16(*(const half8*)(ab + kt * 32),
                                                              B3[kt], acc3, 0, 0, 0);
            if (l15 < 3) {
                int ebase = e0 + wave * 16 + g * 4;
#pragma unroll
                for (int r = 0; r < 4; r++) {
                    int e = ebase + r;
                    if (e < E) out[(size_t)e * 3 + l15] = acc3[r] + bias3;
                }
            }
        }
        __syncthreads();   // protect repr/z2f before next tile's staging
    }
}

extern "C" void kernel_launch(void* const* d_in, const int* in_sizes, int n_in,
                              void* d_out, int out_size, void* d_ws, size_t ws_size,
                              hipStream_t stream) {
    const float* x    = (const float*)d_in[0];
    const int*   ei   = (const int*)d_in[1];
    const float* attr = (const float*)d_in[2];
    const float* tab  = (const float*)d_in[3];
    const float* W1l  = (const float*)d_in[4];
    const float* b1l  = (const float*)d_in[5];
    const float* W1r  = (const float*)d_in[6];
    const float* W2l  = (const float*)d_in[7];
    const float* b2l  = (const float*)d_in[8];
    const float* W2r  = (const float*)d_in[9];
    const float* g1   = (const float*)d_in[10];
    const float* be1  = (const float*)d_in[11];
    const float* m1   = (const float*)d_in[12];
    const float* v1   = (const float*)d_in[13];
    const float* g2   = (const float*)d_in[14];
    const float* be2  = (const float*)d_in[15];
    const float* m2   = (const float*)d_in[16];
    const float* v2   = (const float*)d_in[17];
    const float* Wc1  = (const float*)d_in[18];
    const float* bc1  = (const float*)d_in[19];
    const float* Wc2  = (const float*)d_in[20];
    const float* bc2  = (const float*)d_in[21];
    const float* Wc3  = (const float*)d_in[22];
    const float* bc3  = (const float*)d_in[23];
    float* out = (float*)d_out;

    const int N = in_sizes[0] / NHID;     // 50000
    const int E = in_sizes[1] / 2;        // 800000

    // workspace layout (bytes)
    char* ws = (char*)d_ws;
    int*       rowptr = (int*)(ws + 0);                 // N+1 ints
    int*       cursor = (int*)(ws + 204800);            // N ints
    int*       deg    = (int*)(ws + 409600);            // N ints
    int*       ssrc   = (int*)(ws + 614400);            // E ints
    int*       bsum   = (int*)(ws + 3814400);           // <=256 ints
    int*       bpre   = (int*)(ws + 3815424);           // <=256 ints
    _Float16*  W1T    = (_Float16*)(ws + 3816448);      // 128x288
    _Float16*  W2T    = (_Float16*)(ws + 3890176);      // 64x128
    _Float16*  W3T    = (_Float16*)(ws + 3906560);      // 16x64
    float*     h1     = (float*)(ws + 3908608);         // N*128 f32
    _Float16*  h2f    = (_Float16*)(ws + 3908608 + (size_t)N * NHID * 4);  // N*128 f16

    const int* src = ei;
    const int* dst = ei + E;

    int eblocks = (E + 255) / 256;
    int cblocks = (N + 255) / 256;        // 196
    int nblocks = (N + 15) / 16;
    int ntiles  = (E + EPB - 1) / EPB;
    int cgrid   = ntiles < 2048 ? ntiles : 2048;

    // 0) prep classifier weights (f16, transposed)
    prep_weights<<<144, 256, 0, stream>>>(Wc1, Wc2, Wc3, W1T, W2T, W3T);
    // 1) CSR build
    zero_kernel<<<16, 256, 0, stream>>>((float*)deg, 204800 / 16);
    count_kernel<<<eblocks, 256, 0, stream>>>(dst, deg, E);
    csr_reduce<<<cblocks, 256, 0, stream>>>(deg, bsum, N);
    csr_scan_partials<<<1, 256, 0, stream>>>(bsum, bpre, rowptr, cblocks, N);
    csr_emit<<<cblocks, 256, 0, stream>>>(deg, bpre, rowptr, cursor, N);
    fill_kernel<<<eblocks, 256, 0, stream>>>(src, dst, cursor, ssrc, E);
    // 2) layer 1 -> h1 (fp32)
    sage_layer<<<nblocks, 256, 0, stream>>>(x, rowptr, ssrc, W1l, b1l, W1r,
                                            g1, be1, m1, v1, h1, (_Float16*)nullptr, N);
    // 3) layer 2 -> h2 (f16)
    sage_layer<<<nblocks, 256, 0, stream>>>(h1, rowptr, ssrc, W2l, b2l, W2r,
                                            g2, be2, m2, v2, (float*)nullptr, h2f, N);
    // 4) MFMA edge classifier
    classifier_mfma<<<cgrid, 256, 0, stream>>>(h2f, src, dst, attr, tab,
                                               W1T, bc1, W2T, bc2, W3T, bc3,
                                               out, E, ntiles);
}

// Round 5
// 472.703 us; speedup vs baseline: 10.0085x; 1.2390x over previous
//
#include <hip/hip_runtime.h>
#include <stdint.h>

#define NHID 128
#define EPB 64          // edges per classifier tile
#define RP  296         // padded repr row (f16 elems)
#define Z1P 136         // padded z1 row (f16 elems)
#define Z2P 72          // padded z2 row (f16 elems)

typedef _Float16 half8 __attribute__((ext_vector_type(8)));
typedef float f32x4 __attribute__((ext_vector_type(4)));

// ---------------- zero (16B granularity) ----------------
__global__ void zero_kernel(float* __restrict__ p, size_t n4) {
    size_t i = (size_t)blockIdx.x * blockDim.x + threadIdx.x;
    size_t stride = (size_t)gridDim.x * blockDim.x;
    float4* p4 = (float4*)p;
    float4 z = make_float4(0.f, 0.f, 0.f, 0.f);
    for (size_t j = i; j < n4; j += stride) p4[j] = z;
}

// ---------------- weight prep: fp32 -> f16, transposed ----------------
__global__ void prep_weights(const float* __restrict__ Wc1, const float* __restrict__ Wc2,
                             const float* __restrict__ Wc3,
                             _Float16* __restrict__ W1T, _Float16* __restrict__ W2T,
                             _Float16* __restrict__ W3T) {
    int tid = blockIdx.x * 256 + threadIdx.x;
    if (tid < 288 * 128) {
        int n = tid / 288, k = tid % 288;
        W1T[tid] = (_Float16)Wc1[(size_t)k * 128 + n];
    }
    if (tid < 64 * 128) {
        int n = tid / 128, k = tid % 128;
        W2T[tid] = (_Float16)Wc2[(size_t)k * 64 + n];
    }
    if (tid < 16 * 64) {
        int n = tid / 64, k = tid % 64;
        W3T[tid] = (n < 3) ? (_Float16)Wc3[(size_t)k * 3 + n] : (_Float16)0.f;
    }
}

// ---------------- CSR build ----------------
__global__ void count_kernel(const int* __restrict__ dst, int* __restrict__ deg, int E) {
    int e = blockIdx.x * 256 + threadIdx.x;
    if (e < E) atomicAdd(&deg[dst[e]], 1);
}

__global__ __launch_bounds__(256) void csr_reduce(const int* __restrict__ deg,
                                                  int* __restrict__ bsum, int N) {
    __shared__ int b[256];
    int t = threadIdx.x;
    int i = blockIdx.x * 256 + t;
    int v = (i < N) ? deg[i] : 0;
    b[t] = v;
    __syncthreads();
#pragma unroll
    for (int off = 128; off > 0; off >>= 1) {
        if (t < off) b[t] += b[t + off];
        __syncthreads();
    }
    if (t == 0) bsum[blockIdx.x] = b[0];
}

__global__ __launch_bounds__(256) void csr_scan_partials(const int* __restrict__ bsum,
                                                         int* __restrict__ bpre,
                                                         int* __restrict__ rowptr,
                                                         int nb, int N) {
    __shared__ int b[256];
    int t = threadIdx.x;
    int v = (t < nb) ? bsum[t] : 0;
    b[t] = v;
    __syncthreads();
    int x = v;
#pragma unroll
    for (int off = 1; off < 256; off <<= 1) {
        int y = (t >= off) ? b[t - off] : 0;
        __syncthreads();
        x += y;
        b[t] = x;
        __syncthreads();
    }
    if (t < nb) bpre[t] = x - v;           // exclusive
    if (t == nb - 1) rowptr[N] = x;        // total
}

__global__ __launch_bounds__(256) void csr_emit(const int* __restrict__ deg,
                                                const int* __restrict__ bpre,
                                                int* __restrict__ rowptr,
                                                int* __restrict__ cursor, int N) {
    __shared__ int b[256];
    int t = threadIdx.x;
    int i = blockIdx.x * 256 + t;
    int v = (i < N) ? deg[i] : 0;
    b[t] = v;
    __syncthreads();
    int x = v;
#pragma unroll
    for (int off = 1; off < 256; off <<= 1) {
        int y = (t >= off) ? b[t - off] : 0;
        __syncthreads();
        x += y;
        b[t] = x;
        __syncthreads();
    }
    if (i < N) {
        int excl = bpre[blockIdx.x] + x - v;
        rowptr[i] = excl;
        cursor[i] = excl;
    }
}

__global__ void fill_kernel(const int* __restrict__ src, const int* __restrict__ dst,
                            int* __restrict__ cursor, int* __restrict__ ssrc, int E) {
    int e = blockIdx.x * 256 + threadIdx.x;
    if (e < E) {
        int p = atomicAdd(&cursor[dst[e]], 1);
        ssrc[p] = src[e];
    }
}

// ---------------- fused pull-aggregate + SAGE linear + BN + ReLU ----------------
// 256 threads, 8 nodes/block. Gather: node = tid>>5 (32 lanes/node), q = tid&31
// (feature quad, float4 loads). Short per-thread chains (~deg loads), no reduce.
__global__ __launch_bounds__(256) void sage_layer(
    const float* __restrict__ xin, const int* __restrict__ rowptr,
    const int* __restrict__ ssrc,
    const float* __restrict__ Wl, const float* __restrict__ bl,
    const float* __restrict__ Wr,
    const float* __restrict__ gam, const float* __restrict__ bet,
    const float* __restrict__ mu, const float* __restrict__ var,
    float* __restrict__ out32, _Float16* __restrict__ out16, int N) {
    __shared__ float sA[8][132];   // 132 floats = 528 B rows (16B-aligned)
    __shared__ float sX[8][132];
    int tid = threadIdx.x;
    int i = tid >> 5;              // node slot 0..7
    int q = tid & 31;              // feature quad
    int node0 = blockIdx.x * 8;
    int node = node0 + i;

    { // ---- gather phase
        int rs = rowptr[node], re = rowptr[node + 1];
        float4 acc = make_float4(0.f, 0.f, 0.f, 0.f);
        int e = rs;
        for (; e + 4 <= re; e += 4) {
            int s0 = ssrc[e], s1 = ssrc[e + 1], s2 = ssrc[e + 2], s3 = ssrc[e + 3];
            float4 v0 = *(const float4*)&xin[(size_t)s0 * NHID + q * 4];
            float4 v1 = *(const float4*)&xin[(size_t)s1 * NHID + q * 4];
            float4 v2 = *(const float4*)&xin[(size_t)s2 * NHID + q * 4];
            float4 v3 = *(const float4*)&xin[(size_t)s3 * NHID + q * 4];
            acc.x += (v0.x + v1.x) + (v2.x + v3.x);
            acc.y += (v0.y + v1.y) + (v2.y + v3.y);
            acc.z += (v0.z + v1.z) + (v2.z + v3.z);
            acc.w += (v0.w + v1.w) + (v2.w + v3.w);
        }
        for (; e < re; e++) {
            float4 v = *(const float4*)&xin[(size_t)ssrc[e] * NHID + q * 4];
            acc.x += v.x; acc.y += v.y; acc.z += v.z; acc.w += v.w;
        }
        int deg = re - rs;
        float inv = (deg > 0) ? (1.0f / (float)deg) : 0.f;
        acc.x *= inv; acc.y *= inv; acc.z *= inv; acc.w *= inv;
        *(float4*)&sA[i][q * 4] = acc;
        *(float4*)&sX[i][q * 4] = *(const float4*)&xin[(size_t)node * NHID + q * 4];
    }
    __syncthreads();

    // ---- GEMM phase: o = tid&127, half hh covers 4 nodes
    int o = tid & 127;
    int hh = tid >> 7;
    int i0 = hh * 4;
    float acc[4];
#pragma unroll
    for (int n = 0; n < 4; n++) acc[n] = 0.f;
    for (int k = 0; k < NHID; k += 4) {
        float wl[4], wr[4];
#pragma unroll
        for (int p = 0; p < 4; p++) {
            wl[p] = Wl[(size_t)(k + p) * NHID + o];
            wr[p] = Wr[(size_t)(k + p) * NHID + o];
        }
#pragma unroll
        for (int n = 0; n < 4; n++) {
            float4 a = *(const float4*)&sA[i0 + n][k];
            float4 xx = *(const float4*)&sX[i0 + n][k];
            acc[n] += a.x * wl[0] + a.y * wl[1] + a.z * wl[2] + a.w * wl[3]
                    + xx.x * wr[0] + xx.y * wr[1] + xx.z * wr[2] + xx.w * wr[3];
        }
    }
    float scale = gam[o] * rsqrtf(var[o] + 1e-5f);
    float bias = bet[o];
    float mean = mu[o];
    float bb = bl[o];
#pragma unroll
    for (int n = 0; n < 4; n++) {
        float hv = acc[n] + bb;
        hv = (hv - mean) * scale + bias;
        hv = fmaxf(hv, 0.f);
        if (out32) out32[(size_t)(node0 + i0 + n) * NHID + o] = hv;
        else       out16[(size_t)(node0 + i0 + n) * NHID + o] = (_Float16)hv;
    }
}

// ---------------- MFMA edge classifier, persistent-B grid-stride ----------------
__global__ __launch_bounds__(256, 1) void classifier_mfma(
    const _Float16* __restrict__ h2f, const int* __restrict__ src,
    const int* __restrict__ dst,
    const float* __restrict__ attr, const float* __restrict__ tab,
    const _Float16* __restrict__ W1T, const float* __restrict__ bc1,
    const _Float16* __restrict__ W2T, const float* __restrict__ bc2,
    const _Float16* __restrict__ W3T, const float* __restrict__ bc3,
    float* __restrict__ out, int E, int ntiles) {
    __shared__ _Float16 repr[EPB][RP];    // 37888 B
    __shared__ _Float16 z1s[EPB][Z1P];    // 17408 B
    _Float16* z2f = &repr[0][0];          // [EPB][Z2P] aliases repr

    int tid = threadIdx.x;
    int lane = tid & 63;
    int wave = tid >> 6;
    int l15 = lane & 15;
    int g = lane >> 4;
    int ntb = (wave & 1) * 4;
    int atb = (wave >> 1) * 2;

    // persistent B fragments
    half8 B1[4][9];
    const _Float16* w1base = W1T + (size_t)(ntb * 16 + l15) * 288 + g * 8;
#pragma unroll
    for (int nt = 0; nt < 4; nt++)
#pragma unroll
        for (int kt = 0; kt < 9; kt++)
            B1[nt][kt] = *(const half8*)(w1base + nt * 16 * 288 + kt * 32);
    float bias1[4];
#pragma unroll
    for (int nt = 0; nt < 4; nt++) bias1[nt] = bc1[(ntb + nt) * 16 + l15];
    half8 B2[4];
    const _Float16* w2base = W2T + (size_t)(wave * 16 + l15) * 128 + g * 8;
#pragma unroll
    for (int kt = 0; kt < 4; kt++) B2[kt] = *(const half8*)(w2base + kt * 32);
    float bias2 = bc2[wave * 16 + l15];
    half8 B3[2];
#pragma unroll
    for (int kt = 0; kt < 2; kt++)
        B3[kt] = *(const half8*)(W3T + (size_t)l15 * 64 + kt * 32 + g * 8);
    float bias3 = bc3[l15 < 3 ? l15 : 2];

    for (int t = blockIdx.x; t < ntiles; t += gridDim.x) {
        int e0 = t * EPB;
        { // ---- stage repr
            int el = tid >> 2, p = tid & 3;
            int e = e0 + el; if (e >= E) e = E - 1;
            int s = src[e], d = dst[e];
            const half8* hs = (const half8*)(h2f + (size_t)s * NHID + p * 32);
            const half8* hd = (const half8*)(h2f + (size_t)d * NHID + p * 32);
            half8* r = (half8*)&repr[el][0];
#pragma unroll
            for (int j = 0; j < 4; j++) r[p * 4 + j] = hs[j];
#pragma unroll
            for (int j = 0; j < 4; j++) r[16 + p * 4 + j] = hd[j];
            const float* ssrcp = (p < 2) ? (attr + (size_t)e * 16 + p * 8)
                                         : (tab + (size_t)e * 16 + (p - 2) * 8);
            int doff = (p < 2) ? (32 + p) : (34 + (p - 2));
            float4 a = ((const float4*)ssrcp)[0], b = ((const float4*)ssrcp)[1];
            half8 v;
            v[0] = (_Float16)a.x; v[1] = (_Float16)a.y; v[2] = (_Float16)a.z; v[3] = (_Float16)a.w;
            v[4] = (_Float16)b.x; v[5] = (_Float16)b.y; v[6] = (_Float16)b.z; v[7] = (_Float16)b.w;
            r[doff] = v;
        }
        __syncthreads();

        // ---- GEMM1: 2 atiles x 4 ntiles, B resident
#pragma unroll
        for (int a2 = 0; a2 < 2; a2++) {
            const _Float16* ab = &repr[(atb + a2) * 16 + l15][g * 8];
            f32x4 acc[4];
#pragma unroll
            for (int nt = 0; nt < 4; nt++)
                acc[nt] = (f32x4){bias1[nt], bias1[nt], bias1[nt], bias1[nt]};
#pragma unroll
            for (int kt = 0; kt < 9; kt++) {
                half8 af = *(const half8*)(ab + kt * 32);
#pragma unroll
                for (int nt = 0; nt < 4; nt++)
                    acc[nt] = __builtin_amdgcn_mfma_f32_16x16x32_f16(af, B1[nt][kt], acc[nt], 0, 0, 0);
            }
#pragma unroll
            for (int nt = 0; nt < 4; nt++)
#pragma unroll
                for (int r = 0; r < 4; r++)
                    z1s[(atb + a2) * 16 + g * 4 + r][(ntb + nt) * 16 + l15] =
                        (_Float16)fmaxf(acc[nt][r], 0.f);
        }
        __syncthreads();

        // ---- GEMM2: 4 atiles x 1 ntile (wave) -> z2f (f16, aliases repr)
#pragma unroll
        for (int a = 0; a < 4; a++) {
            const _Float16* ab = &z1s[a * 16 + l15][g * 8];
            f32x4 acc2 = (f32x4){bias2, bias2, bias2, bias2};
#pragma unroll
            for (int kt = 0; kt < 4; kt++)
                acc2 = __builtin_amdgcn_mfma_f32_16x16x32_f16(*(const half8*)(ab + kt * 32),
                                                              B2[kt], acc2, 0, 0, 0);
#pragma unroll
            for (int r = 0; r < 4; r++)
                z2f[(size_t)(a * 16 + g * 4 + r) * Z2P + wave * 16 + l15] =
                    (_Float16)fmaxf(acc2[r], 0.f);
        }
        __syncthreads();

        // ---- layer 3 via MFMA: wave handles atile=wave (16 edges)
        {
            const _Float16* ab = z2f + (size_t)(wave * 16 + l15) * Z2P + g * 8;
            f32x4 acc3 = (f32x4){0.f, 0.f, 0.f, 0.f};
#pragma unroll
            for (int kt = 0; kt < 2; kt++)
                acc3 = __builtin_amdgcn_mfma_f32_16x16x32_f16(*(const half8*)(ab + kt * 32),
                                                              B3[kt], acc3, 0, 0, 0);
            if (l15 < 3) {
                int ebase = e0 + wave * 16 + g * 4;
#pragma unroll
                for (int r = 0; r < 4; r++) {
                    int e = ebase + r;
                    if (e < E) out[(size_t)e * 3 + l15] = acc3[r] + bias3;
                }
            }
        }
        __syncthreads();   // protect repr/z2f before next tile's staging
    }
}

extern "C" void kernel_launch(void* const* d_in, const int* in_sizes, int n_in,
                              void* d_out, int out_size, void* d_ws, size_t ws_size,
                              hipStream_t stream) {
    const float* x    = (const float*)d_in[0];
    const int*   ei   = (const int*)d_in[1];
    const float* attr = (const float*)d_in[2];
    const float* tab  = (const float*)d_in[3];
    const float* W1l  = (const float*)d_in[4];
    const float* b1l  = (const float*)d_in[5];
    const float* W1r  = (const float*)d_in[6];
    const float* W2l  = (const float*)d_in[7];
    const float* b2l  = (const float*)d_in[8];
    const float* W2r  = (const float*)d_in[9];
    const float* g1   = (const float*)d_in[10];
    const float* be1  = (const float*)d_in[11];
    const float* m1   = (const float*)d_in[12];
    const float* v1   = (const float*)d_in[13];
    const float* g2   = (const float*)d_in[14];
    const float* be2  = (const float*)d_in[15];
    const float* m2   = (const float*)d_in[16];
    const float* v2   = (const float*)d_in[17];
    const float* Wc1  = (const float*)d_in[18];
    const float* bc1  = (const float*)d_in[19];
    const float* Wc2  = (const float*)d_in[20];
    const float* bc2  = (const float*)d_in[21];
    const float* Wc3  = (const float*)d_in[22];
    const float* bc3  = (const float*)d_in[23];
    float* out = (float*)d_out;

    const int N = in_sizes[0] / NHID;     // 50000
    const int E = in_sizes[1] / 2;        // 800000

    // workspace layout (bytes)
    char* ws = (char*)d_ws;
    int*       rowptr = (int*)(ws + 0);                 // N+1 ints
    int*       cursor = (int*)(ws + 204800);            // N ints
    int*       deg    = (int*)(ws + 409600);            // N ints
    int*       ssrc   = (int*)(ws + 614400);            // E ints
    int*       bsum   = (int*)(ws + 3814400);           // <=256 ints
    int*       bpre   = (int*)(ws + 3815424);           // <=256 ints
    _Float16*  W1T    = (_Float16*)(ws + 3816448);      // 128x288
    _Float16*  W2T    = (_Float16*)(ws + 3890176);      // 64x128
    _Float16*  W3T    = (_Float16*)(ws + 3906560);      // 16x64
    float*     h1     = (float*)(ws + 3908608);         // N*128 f32
    _Float16*  h2f    = (_Float16*)(ws + 3908608 + (size_t)N * NHID * 4);  // N*128 f16

    const int* src = ei;
    const int* dst = ei + E;

    int eblocks = (E + 255) / 256;
    int cblocks = (N + 255) / 256;        // 196
    int nblocks8 = (N + 7) / 8;           // 6250
    int ntiles  = (E + EPB - 1) / EPB;
    int cgrid   = ntiles < 2048 ? ntiles : 2048;

    // 0) prep classifier weights (f16, transposed)
    prep_weights<<<144, 256, 0, stream>>>(Wc1, Wc2, Wc3, W1T, W2T, W3T);
    // 1) CSR build
    zero_kernel<<<16, 256, 0, stream>>>((float*)deg, 204800 / 16);
    count_kernel<<<eblocks, 256, 0, stream>>>(dst, deg, E);
    csr_reduce<<<cblocks, 256, 0, stream>>>(deg, bsum, N);
    csr_scan_partials<<<1, 256, 0, stream>>>(bsum, bpre, rowptr, cblocks, N);
    csr_emit<<<cblocks, 256, 0, stream>>>(deg, bpre, rowptr, cursor, N);
    fill_kernel<<<eblocks, 256, 0, stream>>>(src, dst, cursor, ssrc, E);
    // 2) layer 1 -> h1 (fp32)
    sage_layer<<<nblocks8, 256, 0, stream>>>(x, rowptr, ssrc, W1l, b1l, W1r,
                                             g1, be1, m1, v1, h1, (_Float16*)nullptr, N);
    // 3) layer 2 -> h2 (f16)
    sage_layer<<<nblocks8, 256, 0, stream>>>(h1, rowptr, ssrc, W2l, b2l, W2r,
                                             g2, be2, m2, v2, (float*)nullptr, h2f, N);
    // 4) MFMA edge classifier
    classifier_mfma<<<cgrid, 256, 0, stream>>>(h2f, src, dst, attr, tab,
                                               W1T, bc1, W2T, bc2, W3T, bc3,
                                               out, E, ntiles);
}